// Round 9
// baseline (343.722 us; speedup 1.0000x reference)
//
#include <hip/hip_runtime.h>
#include <math.h>

#define FIN  512
#define HDIM 128
#define CDIM 40
#define CPAD 48
#define CAP  64   // max in-degree capacity; Poisson(16) => P(deg>=64) ~ 1e-19/node

typedef __attribute__((ext_vector_type(8))) short shortx8;   // 8 bf16 = 4 VGPRs
typedef __attribute__((ext_vector_type(4))) float f32x4;     // MFMA accumulator
typedef __attribute__((ext_vector_type(2))) float floatx2;

__device__ inline unsigned short f2bf(float x) {             // fp32 -> bf16 (RNE)
    unsigned u = __builtin_bit_cast(unsigned, x);
    unsigned r = u + 0x7fffu + ((u >> 16) & 1u);
    return (unsigned short)(r >> 16);
}
__device__ inline float bfu(unsigned short v) { return __builtin_bit_cast(float, (unsigned)v << 16); }
// packed bucket entry: src<<15 | (bits(w)+0x8000)>>16 (15 bits; w in (0,1) => sign=0)
__device__ inline float wdec(unsigned p) { return __builtin_bit_cast(float, (p & 0x7fffu) << 16); }
// fp8 e4m3 (OCP) encode/decode via gfx950 HW converts
__device__ inline unsigned char f2fp8(float x) {
    return (unsigned char)(__builtin_amdgcn_cvt_pk_fp8_f32(x, x, 0, false) & 0xff);
}
__device__ inline floatx2 fp8x2_dec(unsigned short v) {
    return __builtin_amdgcn_cvt_pk_f32_fp8((int)(unsigned)v, false);
}

// ---------- fill buckets + degree sum in ONE packed 64-bit atomic ----------
// cursor[c] += (1<<40) | round(w * 2^32);  old>>40 = slot, low 40 bits accumulate sum(w)
__global__ void k_fill(const int* __restrict__ row, const int* __restrict__ col,
                       const float* __restrict__ w,
                       unsigned long long* __restrict__ cursor,
                       unsigned* __restrict__ bkt, int E) {
    int e = blockIdx.x * blockDim.x + threadIdx.x;
    if (e >= E) return;
    const int c = col[e];
    const float we = w[e];
    const unsigned long long wfix = (unsigned long long)(we * 4294967296.0f); // w<1 => <2^32
    const unsigned long long old = atomicAdd(&cursor[c], (1ULL << 40) | wfix);
    const int p = (int)(old >> 40);
    const unsigned wb = (__builtin_bit_cast(unsigned, we) + 0x8000u) >> 16;   // round, 7-bit mant
    if (p < CAP) bkt[(size_t)c * CAP + p] = ((unsigned)row[e] << 15) | (wb & 0x7fffu);
}

// ---------- fused: weight transpose/cast + degree unpack ----------
#define PREPB 280   // (FIN*HDIM + CPAD*HDIM)/256 = 71680/256
__global__ void k_prep(const float* __restrict__ W1, const float* __restrict__ W2,
                       unsigned short* __restrict__ W1T, unsigned short* __restrict__ W2T,
                       const unsigned long long* __restrict__ cursor,
                       int* __restrict__ cnt, float* __restrict__ dinv, int n) {
    const int b = blockIdx.x;
    if (b < PREPB) {
        const int i = b * 256 + threadIdx.x;
        if (i < FIN * HDIM) {
            const int k = i >> 7, nn = i & 127;
            W1T[nn * FIN + k] = f2bf(W1[i]);
        } else {
            const int j = i - FIN * HDIM;
            const int nn = j >> 7, k = j & 127;
            W2T[j] = (nn < CDIM) ? f2bf(W2[k * CDIM + nn]) : (unsigned short)0;
        }
    } else {
        const int i = (b - PREPB) * 256 + threadIdx.x;
        if (i < n) {
            const unsigned long long p = cursor[i];
            cnt[i] = min((int)(p >> 40), CAP);
            const float wsum = (float)(p & ((1ULL << 40) - 1)) * 2.3283064365386963e-10f;
            dinv[i] = rsqrtf(1.0f + wsum);
        }
    }
}

// ---------- GEMM1 streaming (no LDS): wave owns 16 rows x 128 cols ----------
// A-frag straight from global fp32 (read-once, full lines); B-frags from L2-hot W1T.
__global__ __launch_bounds__(256) void k_gemm1(const float* __restrict__ A,
                                               const unsigned short* __restrict__ W1T,
                                               const float* __restrict__ dinv,
                                               unsigned char* __restrict__ h1f8, int M) {
    const int wid = blockIdx.x * 4 + (threadIdx.x >> 6);
    const int m0  = wid * 16;
    if (m0 >= M) return;
    const int lane = threadIdx.x & 63;
    const int quad = lane >> 4;
    const int mr   = lane & 15;

    f32x4 acc[8];
#pragma unroll
    for (int i = 0; i < 8; i++) acc[i] = (f32x4)0.f;

    const float* arow = A + (size_t)(m0 + mr) * FIN + quad * 8;          // lane's A row
    const unsigned short* bbase = W1T + (size_t)mr * FIN + quad * 8;     // lane's B row

#pragma unroll 2
    for (int k0 = 0; k0 < FIN; k0 += 32) {
        const float4 a0 = *(const float4*)(arow + k0);
        const float4 a1 = *(const float4*)(arow + k0 + 4);
        shortx8 af;
        af[0] = (short)f2bf(a0.x); af[1] = (short)f2bf(a0.y);
        af[2] = (short)f2bf(a0.z); af[3] = (short)f2bf(a0.w);
        af[4] = (short)f2bf(a1.x); af[5] = (short)f2bf(a1.y);
        af[6] = (short)f2bf(a1.z); af[7] = (short)f2bf(a1.w);
        shortx8 bf[8];
#pragma unroll
        for (int nt = 0; nt < 8; nt++)
            bf[nt] = *(const shortx8*)(bbase + (size_t)nt * 16 * FIN + k0);
#pragma unroll
        for (int nt = 0; nt < 8; nt++)
            acc[nt] = __builtin_amdgcn_mfma_f32_16x16x32_bf16(af, bf[nt], acc[nt], 0, 0, 0);
    }
    // C layout: col = mr (N), row = quad*4 + r (M)
#pragma unroll
    for (int r = 0; r < 4; r++) {
        const int om = m0 + quad * 4 + r;
        const float dv = dinv[om];
#pragma unroll
        for (int nt = 0; nt < 8; nt++)
            h1f8[(size_t)om * HDIM + nt * 16 + mr] = f2fp8(dv * acc[nt][r]);
    }
}

// ---------- gather layer1: x1 = relu(dinv*(sum w*h1'[r] + h1'[self]) + b1) ----------
// wave per node, 64 lanes x 2 feats (fp8 pair); 8-deep unroll, packed 4B bucket entries
__global__ __launch_bounds__(256) void k_gather1(
    const int* __restrict__ cnt_arr, const unsigned* __restrict__ bkt,
    const unsigned char* __restrict__ h1f8,   // fp8 rows, 128 B pitch
    const float* __restrict__ dinv, const float* __restrict__ b1,
    unsigned* __restrict__ x1u, int n_nodes) {
    const int node = blockIdx.x * 4 + (threadIdx.x >> 6);
    const int lane = threadIdx.x & 63;
    if (node >= n_nodes) return;
    const int cnt = cnt_arr[node];
    const unsigned* base = bkt + (size_t)node * CAP;
    const int loff = lane * 2;
    float a0 = 0.f, a1 = 0.f, c0 = 0.f, c1 = 0.f;
    int s = 0;
    for (; s + 8 <= cnt; s += 8) {
        const uint4 qa = *(const uint4*)(base + s);
        const uint4 qb = *(const uint4*)(base + s + 4);
        const unsigned short v0 = *(const unsigned short*)(h1f8 + (size_t)(qa.x >> 15) * HDIM + loff);
        const unsigned short v1 = *(const unsigned short*)(h1f8 + (size_t)(qa.y >> 15) * HDIM + loff);
        const unsigned short v2 = *(const unsigned short*)(h1f8 + (size_t)(qa.z >> 15) * HDIM + loff);
        const unsigned short v3 = *(const unsigned short*)(h1f8 + (size_t)(qa.w >> 15) * HDIM + loff);
        const unsigned short v4 = *(const unsigned short*)(h1f8 + (size_t)(qb.x >> 15) * HDIM + loff);
        const unsigned short v5 = *(const unsigned short*)(h1f8 + (size_t)(qb.y >> 15) * HDIM + loff);
        const unsigned short v6 = *(const unsigned short*)(h1f8 + (size_t)(qb.z >> 15) * HDIM + loff);
        const unsigned short v7 = *(const unsigned short*)(h1f8 + (size_t)(qb.w >> 15) * HDIM + loff);
        const floatx2 f0 = fp8x2_dec(v0), f1 = fp8x2_dec(v1), f2 = fp8x2_dec(v2), f3 = fp8x2_dec(v3);
        const floatx2 f4 = fp8x2_dec(v4), f5 = fp8x2_dec(v5), f6 = fp8x2_dec(v6), f7 = fp8x2_dec(v7);
        a0 += wdec(qa.x) * f0.x + wdec(qa.y) * f1.x + wdec(qa.z) * f2.x + wdec(qa.w) * f3.x;
        a1 += wdec(qa.x) * f0.y + wdec(qa.y) * f1.y + wdec(qa.z) * f2.y + wdec(qa.w) * f3.y;
        c0 += wdec(qb.x) * f4.x + wdec(qb.y) * f5.x + wdec(qb.z) * f6.x + wdec(qb.w) * f7.x;
        c1 += wdec(qb.x) * f4.y + wdec(qb.y) * f5.y + wdec(qb.z) * f6.y + wdec(qb.w) * f7.y;
    }
    for (; s + 4 <= cnt; s += 4) {
        const uint4 qa = *(const uint4*)(base + s);
        const unsigned short v0 = *(const unsigned short*)(h1f8 + (size_t)(qa.x >> 15) * HDIM + loff);
        const unsigned short v1 = *(const unsigned short*)(h1f8 + (size_t)(qa.y >> 15) * HDIM + loff);
        const unsigned short v2 = *(const unsigned short*)(h1f8 + (size_t)(qa.z >> 15) * HDIM + loff);
        const unsigned short v3 = *(const unsigned short*)(h1f8 + (size_t)(qa.w >> 15) * HDIM + loff);
        const floatx2 f0 = fp8x2_dec(v0), f1 = fp8x2_dec(v1), f2 = fp8x2_dec(v2), f3 = fp8x2_dec(v3);
        a0 += wdec(qa.x) * f0.x + wdec(qa.y) * f1.x + wdec(qa.z) * f2.x + wdec(qa.w) * f3.x;
        a1 += wdec(qa.x) * f0.y + wdec(qa.y) * f1.y + wdec(qa.z) * f2.y + wdec(qa.w) * f3.y;
    }
    for (; s < cnt; s++) {
        const unsigned p = base[s];
        const unsigned short v = *(const unsigned short*)(h1f8 + (size_t)(p >> 15) * HDIM + loff);
        const floatx2 f = fp8x2_dec(v);
        a0 += wdec(p) * f.x;
        a1 += wdec(p) * f.y;
    }
    a0 += c0; a1 += c1;
    const float dl = dinv[node];
    const unsigned short vs = *(const unsigned short*)(h1f8 + (size_t)node * HDIM + loff);
    const floatx2 fs = fp8x2_dec(vs);                 // self-loop (h1' already dinv-scaled)
    a0 = fmaxf(dl * (a0 + fs.x) + b1[loff], 0.f);
    a1 = fmaxf(dl * (a1 + fs.y) + b1[loff + 1], 0.f);
    x1u[(size_t)node * 64 + lane] = (unsigned)f2bf(a0) | ((unsigned)f2bf(a1) << 16);
}

// ---------- GEMM2 streaming (no LDS): wave owns 16 rows x 48 cols ----------
__global__ __launch_bounds__(256) void k_gemm2(const unsigned short* __restrict__ x1bf,
                                               const unsigned short* __restrict__ W2T,
                                               const float* __restrict__ dinv,
                                               unsigned short* __restrict__ h2a,
                                               unsigned short* __restrict__ h2b, int M) {
    const int wid = blockIdx.x * 4 + (threadIdx.x >> 6);
    const int m0  = wid * 16;
    if (m0 >= M) return;
    const int lane = threadIdx.x & 63;
    const int quad = lane >> 4;
    const int mr   = lane & 15;

    f32x4 acc[3];
#pragma unroll
    for (int i = 0; i < 3; i++) acc[i] = (f32x4)0.f;

    const unsigned short* xrow  = x1bf + (size_t)(m0 + mr) * HDIM + quad * 8;
    const unsigned short* bbase = W2T + (size_t)mr * HDIM + quad * 8;

#pragma unroll
    for (int k0 = 0; k0 < HDIM; k0 += 32) {
        const shortx8 af = *(const shortx8*)(xrow + k0);
#pragma unroll
        for (int nt = 0; nt < 3; nt++) {
            const shortx8 bf = *(const shortx8*)(bbase + (size_t)nt * 16 * HDIM + k0);
            acc[nt] = __builtin_amdgcn_mfma_f32_16x16x32_bf16(af, bf, acc[nt], 0, 0, 0);
        }
    }
#pragma unroll
    for (int r = 0; r < 4; r++) {
        const int om = m0 + quad * 4 + r;
        const float dv = dinv[om];
#pragma unroll
        for (int nt = 0; nt < 2; nt++)    // cols 0..31 -> h2a (one 64B line/row)
            h2a[(size_t)om * 32 + nt * 16 + mr] = f2bf(dv * acc[nt][r]);
        if (mr < 8)                        // cols 32..39 -> h2b (L2-resident, 800KB)
            h2b[(size_t)om * 8 + mr] = f2bf(dv * acc[2][r]);
    }
}

// ---------- gather layer2 + self-loop + bias + log_softmax, wave/node ----------
__global__ __launch_bounds__(256) void k_gather2(
    const int* __restrict__ cnt_arr, const unsigned* __restrict__ bkt,
    const unsigned short* __restrict__ h2a, const unsigned short* __restrict__ h2b,
    const float* __restrict__ dinv, const float* __restrict__ b2,
    float* __restrict__ out, int n_nodes) {
    const int node = blockIdx.x * 4 + (threadIdx.x >> 6);
    const int lane = threadIdx.x & 63;
    if (node >= n_nodes) return;
    const bool act = lane < CDIM;
    const int cnt = cnt_arr[node];
    const unsigned* base = bkt + (size_t)node * CAP;
    // lane -> {array, stride}: cols 0..31 from h2a (stride 32), 32..39 from h2b (stride 8)
    const unsigned short* hb = (lane < 32) ? (h2a + lane) : (h2b + (lane & 7));
    const int hstride = (lane < 32) ? 32 : 8;
    float acc = 0.f, accb = 0.f;
    int s = 0;
    for (; s + 4 <= cnt; s += 4) {
        const uint4 q = *(const uint4*)(base + s);
        if (act) {
            acc  += wdec(q.x) * bfu(hb[(size_t)(q.x >> 15) * hstride])
                  + wdec(q.y) * bfu(hb[(size_t)(q.y >> 15) * hstride]);
            accb += wdec(q.z) * bfu(hb[(size_t)(q.z >> 15) * hstride])
                  + wdec(q.w) * bfu(hb[(size_t)(q.w >> 15) * hstride]);
        }
    }
    for (; s < cnt; s++) {
        const unsigned p = base[s];
        if (act) acc += wdec(p) * bfu(hb[(size_t)(p >> 15) * hstride]);
    }
    acc += accb;
    if (act) {
        const float dl = dinv[node];
        acc = dl * (acc + bfu(hb[(size_t)node * hstride])) + b2[lane];
    }
    float m = act ? acc : -INFINITY;
#pragma unroll
    for (int off = 32; off; off >>= 1) m = fmaxf(m, __shfl_xor(m, off));
    float se = act ? expf(acc - m) : 0.f;
#pragma unroll
    for (int off = 32; off; off >>= 1) se += __shfl_xor(se, off);
    if (act) out[(size_t)node * CDIM + lane] = acc - m - logf(se);
}

extern "C" void kernel_launch(void* const* d_in, const int* in_sizes, int n_in,
                              void* d_out, int out_size, void* d_ws, size_t ws_size,
                              hipStream_t stream) {
    const float* features = (const float*)d_in[0];
    const int*   eidx     = (const int*)d_in[1];
    const float* ew       = (const float*)d_in[2];
    const float* W1       = (const float*)d_in[3];
    const float* b1       = (const float*)d_in[4];
    const float* W2       = (const float*)d_in[5];
    const float* b2       = (const float*)d_in[6];
    float* out = (float*)d_out;

    const int Nn = in_sizes[0] / FIN;   // 50000
    const int E  = in_sizes[2];         // 800000
    const int* row = eidx;
    const int* col = eidx + E;

    char* ws = (char*)d_ws;
    size_t off = 0;
    auto alloc = [&](size_t bytes) { void* p = ws + off; off += (bytes + 255) & ~(size_t)255; return p; };
    unsigned long long* cursor = (unsigned long long*)alloc((size_t)Nn * 8);
    int*      cnt          = (int*)     alloc((size_t)Nn * 4);
    float*    dinv         = (float*)   alloc((size_t)Nn * 4);
    unsigned* bkt          = (unsigned*)alloc((size_t)Nn * CAP * 4);
    unsigned short* W1T    = (unsigned short*)alloc((size_t)FIN * HDIM * 2);
    unsigned short* W2T    = (unsigned short*)alloc((size_t)CPAD * HDIM * 2);
    unsigned char*  h1f8   = (unsigned char*) alloc((size_t)Nn * HDIM);
    unsigned short* x1bf   = (unsigned short*)alloc((size_t)Nn * HDIM * 2);
    unsigned short* h2a    = (unsigned short*)alloc((size_t)Nn * 32 * 2);
    unsigned short* h2b    = (unsigned short*)alloc((size_t)Nn * 8 * 2);

    // bucket build: one packed 64-bit atomic per edge (slot | degree-sum)
    hipMemsetAsync(cursor, 0, (size_t)Nn * 8, stream);
    k_fill<<<(E + 255) / 256, 256, 0, stream>>>(row, col, ew, cursor, bkt, E);
    // fused weight prep + degree unpack
    k_prep<<<PREPB + (Nn + 255) / 256, 256, 0, stream>>>(W1, W2, W1T, W2T,
                                                         cursor, cnt, dinv, Nn);
    // layer 1  (3125 waves = 782 blocks of 4 waves)
    const int nwave1 = (Nn + 15) / 16;
    k_gemm1<<<(nwave1 + 3) / 4, 256, 0, stream>>>(features, W1T, dinv, h1f8, Nn);
    k_gather1<<<(Nn + 3) / 4, 256, 0, stream>>>(cnt, bkt, h1f8, dinv, b1,
                                                (unsigned*)x1bf, Nn);
    // layer 2
    k_gemm2<<<(nwave1 + 3) / 4, 256, 0, stream>>>(x1bf, W2T, dinv, h2a, h2b, Nn);
    k_gather2<<<(Nn + 3) / 4, 256, 0, stream>>>(cnt, bkt, h2a, h2b, dinv, b2, out, Nn);
}